// Round 9
// baseline (256.071 us; speedup 1.0000x reference)
//
#include <hip/hip_runtime.h>
#include <hip/hip_bf16.h>
#include <math.h>

namespace {
constexpr int Cc = 256;
constexpr int Hh = 128;
constexpr int Ww = 256;
constexpr int HW  = Hh * Ww;        // 32768
constexpr int CHW = Cc * HW;        // 8388608
constexpr int P     = 16;           // pixels per block
constexpr int NTHR  = 512;          // 8 waves; 32 channel groups
constexpr int CPG   = 8;            // channels per thread
constexpr int TILES = HW / P;       // 2048 tiles per batch
}

__device__ __forceinline__ unsigned short f2bf(float f) {
    __hip_bfloat16 h = __float2bfloat16(f);
    return __builtin_bit_cast(unsigned short, h);
}
__device__ __forceinline__ float bf2f(unsigned short u) {
    return __uint_as_float(((unsigned int)u) << 16);
}

// Forced-MLP gather: issue a load cluster via volatile inline asm (compiler
// cannot re-serialize it; r4-r8 showed hipcc sinks C-level load clusters to
// ~1 in-flight load/wave -> 2.5-2.7 TB/s latency-bound). One manual
// s_waitcnt vmcnt(0) + sched_barrier(0) fences the compute (rule #18).
#define GLD(dst, addr) \
    asm volatile("global_load_dword %0, %1, off" : "=v"(dst) : "v"(addr))
#define GLD_OFF(dst, addr, imm) \
    asm volatile("global_load_dword %0, %1, off offset:" #imm : "=v"(dst) : "v"(addr))

// record_len module constant {5,4,3,2}: N = 5-b, start s = 5b - b(b-1)/2.
// pairwise_t_matrix[b,0,0] is exactly identity (M[:,i,i]=eye) -> agent 0 = direct load.

template<int N>
__device__ __forceinline__ void run_body(const float* __restrict__ x,
                                         const float* __restrict__ tmat,
                                         float* __restrict__ out,
                                         int b, int tile, int tid,
                                         ushort4 (*feat)[P + 1],
                                         float (*dl)[5][P])
{
    constexpr int A = N - 1;            // gathered agents (1..4)
    const int lane = tid & 63;
    const int wv   = tid >> 6;
    const int pix  = lane & (P - 1);
    const int sub  = lane >> 4;         // 0..3
    const int g    = wv * 4 + sub;      // channel group 0..31
    const int cbase = g * CPG;

    const int p = tile * P + pix;       // 16 consecutive pixels in one row
    const int h = p >> 8;
    const int w = p & (Ww - 1);
    const int s = 5 * b - (b * (b - 1)) / 2;

    const float gx = -1.0f + 2.0f * (float)w / (float)(Ww - 1);
    const float gy = -1.0f + 2.0f * (float)h / (float)(Hh - 1);

    // Row-factored bilinear taps per gathered agent: base offset + 4 weights,
    // OOB validity folded into the weights (zero padding semantics).
    int   offp[A];
    float wxA[A], wxB[A], wyA[A], wyB[A];
#pragma unroll
    for (int a = 0; a < A; ++a) {
        const int j = a + 1;
        const float* Mp = tmat + (size_t)(b * 25 + j) * 16;
        const float a00 = Mp[0];
        const float a01 = Mp[1] * ((float)Hh / (float)Ww);
        const float a02 = Mp[3] * (2.0f / (4.0f * 0.4f * (float)Ww));
        const float a10 = Mp[4] * ((float)Ww / (float)Hh);
        const float a11 = Mp[5];
        const float a12 = Mp[7] * (2.0f / (4.0f * 0.4f * (float)Hh));
        const float px = (a00 * gx + a01 * gy + a02 + 1.0f) * 0.5f * (float)(Ww - 1);
        const float py = (a10 * gx + a11 * gy + a12 + 1.0f) * 0.5f * (float)(Hh - 1);
        const float x0f = floorf(px), y0f = floorf(py);
        const float fx = px - x0f, fy = py - y0f;
        const int x0 = (int)x0f, y0 = (int)y0f;
        const int xc = min(max(x0, 0), Ww - 2);
        const int yc = min(max(y0, 0), Hh - 2);
        const bool xin = (x0 >= 0) & (x0 <= Ww - 2);
        const bool yin = (y0 >= 0) & (y0 <= Hh - 2);
        wxA[a] = xin ? (1.f - fx) : ((x0 == -1)     ? fx         : 0.f);
        wxB[a] = xin ? fx         : ((x0 == Ww - 1) ? (1.f - fx) : 0.f);
        wyA[a] = yin ? (1.f - fy) : ((y0 == -1)     ? fy         : 0.f);
        wyB[a] = yin ? fy         : ((y0 == Hh - 1) ? (1.f - fy) : 0.f);
        offp[a] = yc * Ww + xc;
    }

    const float* xb0 = x + (size_t)s * CHW;

    // ---- pass 1: per k, issue the full 1+4A load cluster in asm (stays
    // 17-deep in flight), then wait once and compute ----
    float f0[CPG];
    float dj[5] = {0.f, 0.f, 0.f, 0.f, 0.f};
#pragma unroll
    for (int k = 0; k < CPG; ++k) {
        const float* pc = xb0 + (size_t)(cbase + k) * HW;
        float v0;
        float t[A][4];

        GLD(v0, pc + p);                     // identity warp: exact, coalesced
#pragma unroll
        for (int a = 0; a < A; ++a) {
            const float* q = pc + (size_t)(a + 1) * CHW + offp[a];
            GLD(t[a][0], q);                 // row yc:   x, x+1
            GLD_OFF(t[a][1], q, 4);
            GLD_OFF(t[a][2], q, 1024);       // row yc+1: x, x+1  (Ww*4 = 1024)
            GLD_OFF(t[a][3], q, 1028);
        }
        asm volatile("s_waitcnt vmcnt(0)" ::: "memory");
        __builtin_amdgcn_sched_barrier(0);

        f0[k] = v0;
        dj[0] = fmaf(v0, v0, dj[0]);
        unsigned short pk[4] = {0, 0, 0, 0};
#pragma unroll
        for (int a = 0; a < A; ++a) {
            const float v = wyA[a] * (wxA[a] * t[a][0] + wxB[a] * t[a][1])
                          + wyB[a] * (wxA[a] * t[a][2] + wxB[a] * t[a][3]);
            dj[a + 1] = fmaf(v0, v, dj[a + 1]);
            pk[a] = f2bf(v);
        }
        ushort4 u4; u4.x = pk[0]; u4.y = pk[1]; u4.z = pk[2]; u4.w = pk[3];
        feat[cbase + k][pix] = u4;
    }

    // ---- dot reduce: 4 subgroups via shuffle, 8 waves via LDS ----
#pragma unroll
    for (int j = 0; j < N; ++j) {
        dj[j] += __shfl_xor(dj[j], 16);
        dj[j] += __shfl_xor(dj[j], 32);
    }
    if (sub == 0) {
#pragma unroll
        for (int j = 0; j < N; ++j) dl[wv][j][pix] = dj[j];
    }
    __syncthreads();

    // ---- softmax over j (per pixel, redundantly per thread) ----
    float e[5] = {0.f, 0.f, 0.f, 0.f, 0.f};
    {
        float sc[N];
#pragma unroll
        for (int j = 0; j < N; ++j) {
            float t = 0.f;
#pragma unroll
            for (int wvi = 0; wvi < 8; ++wvi) t += dl[wvi][j][pix];
            sc[j] = t * (1.0f / 16.0f);     // * 1/sqrt(C)
        }
        float m = sc[0];
#pragma unroll
        for (int j = 1; j < N; ++j) m = fmaxf(m, sc[j]);
        float sum = 0.f;
#pragma unroll
        for (int j = 0; j < N; ++j) { e[j] = __expf(sc[j] - m); sum += e[j]; }
        const float inv = 1.0f / sum;
#pragma unroll
        for (int j = 0; j < N; ++j) e[j] *= inv;
    }

    // ---- pass 2: weighted sum from regs + LDS, streamed out ----
    float* ob = out + (size_t)b * CHW + p;
#pragma unroll
    for (int k = 0; k < CPG; ++k) {
        const ushort4 u = feat[cbase + k][pix];
        float acc = e[0] * f0[k];
        if constexpr (N > 1) acc = fmaf(e[1], bf2f(u.x), acc);
        if constexpr (N > 2) acc = fmaf(e[2], bf2f(u.y), acc);
        if constexpr (N > 3) acc = fmaf(e[3], bf2f(u.z), acc);
        if constexpr (N > 4) acc = fmaf(e[4], bf2f(u.w), acc);
        __builtin_nontemporal_store(acc, ob + (size_t)(cbase + k) * HW);
    }
}

__global__ __launch_bounds__(NTHR, 4)
void atten_fused(const float* __restrict__ x,
                 const float* __restrict__ tmat,
                 float* __restrict__ out)
{
    __shared__ ushort4 feat[Cc][P + 1];   // bf16 gathered agents, ~34.8 KB
    __shared__ float   dl[8][5][P];       // per-wave partial dots, 2.5 KB

    // Batch-major order (round-4 proven: light batch drains last).
    const int b    = blockIdx.x >> 11;    // TILES = 2048 per batch
    const int tile = blockIdx.x & (TILES - 1);
    const int tid  = threadIdx.x;

    if      (b == 0) run_body<5>(x, tmat, out, 0, tile, tid, feat, dl);
    else if (b == 1) run_body<4>(x, tmat, out, 1, tile, tid, feat, dl);
    else if (b == 2) run_body<3>(x, tmat, out, 2, tile, tid, feat, dl);
    else             run_body<2>(x, tmat, out, 3, tile, tid, feat, dl);
}

extern "C" void kernel_launch(void* const* d_in, const int* in_sizes, int n_in,
                              void* d_out, int out_size, void* d_ws, size_t ws_size,
                              hipStream_t stream) {
    const float* x    = (const float*)d_in[0];
    // d_in[1] = rm (unused by reference output), d_in[2] = record_len (constant)
    const float* tmat = (const float*)d_in[3];
    float* out = (float*)d_out;
    dim3 grid(4 * TILES);
    dim3 block(NTHR);
    hipLaunchKernelGGL(atten_fused, grid, block, 0, stream, x, tmat, out);
}

// Round 10
// 195.632 us; speedup vs baseline: 1.3089x; 1.3089x over previous
//
#include <hip/hip_runtime.h>
#include <hip/hip_bf16.h>
#include <math.h>

namespace {
constexpr int Cc = 256;
constexpr int Hh = 128;
constexpr int Ww = 256;
constexpr int HW  = Hh * Ww;        // 32768
constexpr int CHW = Cc * HW;        // 8388608
constexpr int P     = 32;           // pixels per block (grain experiment: 16->32)
constexpr int NTHR  = 512;          // 8 waves; 16 channel groups
constexpr int CPG   = 16;           // channels per thread
constexpr int TILES = HW / P;       // 1024 tiles per batch
}

struct alignas(4) F2 { float x, y; };   // 4B-aligned 8B pair load (dwordx2)

__device__ __forceinline__ unsigned short f2bf(float f) {
    __hip_bfloat16 h = __float2bfloat16(f);
    return __builtin_bit_cast(unsigned short, h);
}
__device__ __forceinline__ float bf2f(unsigned short u) {
    return __uint_as_float(((unsigned int)u) << 16);
}

// record_len module constant {5,4,3,2}: N = 5-b, start s = 5b - b(b-1)/2.
// pairwise_t_matrix[b,0,0] is exactly identity (M[:,i,i]=eye) -> agent 0 = direct load.
// Grain theory (r9 post-mortem): BW pinned at 2.5-2.7 TB/s across occupancy
// 36-62%, MLP 1-17 deep, instr contiguity 64-256B => saturated-stage equilibrium
// set by ~72B-per-line tap consumption. P=32 makes tap windows ~140B/row.

template<int N>
__device__ __forceinline__ void run_body(const float* __restrict__ x,
                                         const float* __restrict__ tmat,
                                         float* __restrict__ out,
                                         int b, int tile, int tid,
                                         ushort4 (*feat)[P + 1],
                                         float (*dl)[5][P])
{
    constexpr int A = N - 1;            // gathered agents (1..4)
    const int lane = tid & 63;
    const int wv   = tid >> 6;
    const int pix  = lane & (P - 1);    // 0..31
    const int sub  = lane >> 5;         // 0..1
    const int g    = wv * 2 + sub;      // channel group 0..15
    const int cbase = g * CPG;

    const int p = tile * P + pix;       // 32 consecutive pixels in one row
    const int h = p >> 8;
    const int w = p & (Ww - 1);
    const int s = 5 * b - (b * (b - 1)) / 2;

    const float gx = -1.0f + 2.0f * (float)w / (float)(Ww - 1);
    const float gy = -1.0f + 2.0f * (float)h / (float)(Hh - 1);

    // Row-factored bilinear taps per gathered agent: base offset + 4 weights,
    // OOB validity folded into the weights (zero padding semantics).
    int   offp[A];
    float wxA[A], wxB[A], wyA[A], wyB[A];
#pragma unroll
    for (int a = 0; a < A; ++a) {
        const int j = a + 1;
        const float* Mp = tmat + (size_t)(b * 25 + j) * 16;
        const float a00 = Mp[0];
        const float a01 = Mp[1] * ((float)Hh / (float)Ww);
        const float a02 = Mp[3] * (2.0f / (4.0f * 0.4f * (float)Ww));
        const float a10 = Mp[4] * ((float)Ww / (float)Hh);
        const float a11 = Mp[5];
        const float a12 = Mp[7] * (2.0f / (4.0f * 0.4f * (float)Hh));
        const float px = (a00 * gx + a01 * gy + a02 + 1.0f) * 0.5f * (float)(Ww - 1);
        const float py = (a10 * gx + a11 * gy + a12 + 1.0f) * 0.5f * (float)(Hh - 1);
        const float x0f = floorf(px), y0f = floorf(py);
        const float fx = px - x0f, fy = py - y0f;
        const int x0 = (int)x0f, y0 = (int)y0f;
        const int xc = min(max(x0, 0), Ww - 2);
        const int yc = min(max(y0, 0), Hh - 2);
        const bool xin = (x0 >= 0) & (x0 <= Ww - 2);
        const bool yin = (y0 >= 0) & (y0 <= Hh - 2);
        wxA[a] = xin ? (1.f - fx) : ((x0 == -1)     ? fx         : 0.f);
        wxB[a] = xin ? fx         : ((x0 == Ww - 1) ? (1.f - fx) : 0.f);
        wyA[a] = yin ? (1.f - fy) : ((y0 == -1)     ? fy         : 0.f);
        wyB[a] = yin ? fy         : ((y0 == Hh - 1) ? (1.f - fy) : 0.f);
        offp[a] = yc * Ww + xc;
    }

    const float* xb0 = x + (size_t)s * CHW;

    // ---- pass 1: agent0 direct + per-agent dwordx2 row-pair taps ----
    float f0[CPG];
    float dj[5] = {0.f, 0.f, 0.f, 0.f, 0.f};
#pragma unroll
    for (int k = 0; k < CPG; ++k) {
        const float* pc = xb0 + (size_t)(cbase + k) * HW;
        const float v0 = pc[p];            // identity warp: exact, coalesced
        f0[k] = v0;
        dj[0] = fmaf(v0, v0, dj[0]);
        unsigned short pk[4] = {0, 0, 0, 0};
#pragma unroll
        for (int a = 0; a < A; ++a) {
            const float* q = pc + (size_t)(a + 1) * CHW + offp[a];
            const F2 r0 = *(const F2*)q;          // row yc:   [x, x+1]
            const F2 r1 = *(const F2*)(q + Ww);   // row yc+1: [x, x+1]
            const float v = wyA[a] * (wxA[a] * r0.x + wxB[a] * r0.y)
                          + wyB[a] * (wxA[a] * r1.x + wxB[a] * r1.y);
            dj[a + 1] = fmaf(v0, v, dj[a + 1]);
            pk[a] = f2bf(v);
        }
        ushort4 u4; u4.x = pk[0]; u4.y = pk[1]; u4.z = pk[2]; u4.w = pk[3];
        feat[cbase + k][pix] = u4;
    }

    // ---- dot reduce: 2 subgroups via shuffle, 8 waves via LDS ----
#pragma unroll
    for (int j = 0; j < N; ++j) dj[j] += __shfl_xor(dj[j], 32);
    if (sub == 0) {
#pragma unroll
        for (int j = 0; j < N; ++j) dl[wv][j][pix] = dj[j];
    }
    __syncthreads();

    // ---- softmax over j (per pixel, redundantly per thread) ----
    float e[5] = {0.f, 0.f, 0.f, 0.f, 0.f};
    {
        float sc[N];
#pragma unroll
        for (int j = 0; j < N; ++j) {
            float t = 0.f;
#pragma unroll
            for (int wvi = 0; wvi < 8; ++wvi) t += dl[wvi][j][pix];
            sc[j] = t * (1.0f / 16.0f);     // * 1/sqrt(C)
        }
        float m = sc[0];
#pragma unroll
        for (int j = 1; j < N; ++j) m = fmaxf(m, sc[j]);
        float sum = 0.f;
#pragma unroll
        for (int j = 0; j < N; ++j) { e[j] = __expf(sc[j] - m); sum += e[j]; }
        const float inv = 1.0f / sum;
#pragma unroll
        for (int j = 0; j < N; ++j) e[j] *= inv;
    }

    // ---- pass 2: weighted sum from regs + LDS, streamed out ----
    float* ob = out + (size_t)b * CHW + p;
#pragma unroll
    for (int k = 0; k < CPG; ++k) {
        const ushort4 u = feat[cbase + k][pix];
        float acc = e[0] * f0[k];
        if constexpr (N > 1) acc = fmaf(e[1], bf2f(u.x), acc);
        if constexpr (N > 2) acc = fmaf(e[2], bf2f(u.y), acc);
        if constexpr (N > 3) acc = fmaf(e[3], bf2f(u.z), acc);
        if constexpr (N > 4) acc = fmaf(e[4], bf2f(u.w), acc);
        __builtin_nontemporal_store(acc, ob + (size_t)(cbase + k) * HW);
    }
}

__global__ __launch_bounds__(NTHR, 4)
void atten_fused(const float* __restrict__ x,
                 const float* __restrict__ tmat,
                 float* __restrict__ out)
{
    __shared__ ushort4 feat[Cc][P + 1];   // bf16 gathered agents, ~66 KB
    __shared__ float   dl[8][5][P];       // per-wave partial dots, 5 KB

    // Batch-major order (round-4/6 proven: light batch drains last).
    const int b    = blockIdx.x >> 10;    // TILES = 1024 per batch
    const int tile = blockIdx.x & (TILES - 1);
    const int tid  = threadIdx.x;

    if      (b == 0) run_body<5>(x, tmat, out, 0, tile, tid, feat, dl);
    else if (b == 1) run_body<4>(x, tmat, out, 1, tile, tid, feat, dl);
    else if (b == 2) run_body<3>(x, tmat, out, 2, tile, tid, feat, dl);
    else             run_body<2>(x, tmat, out, 3, tile, tid, feat, dl);
}

extern "C" void kernel_launch(void* const* d_in, const int* in_sizes, int n_in,
                              void* d_out, int out_size, void* d_ws, size_t ws_size,
                              hipStream_t stream) {
    const float* x    = (const float*)d_in[0];
    // d_in[1] = rm (unused by reference output), d_in[2] = record_len (constant)
    const float* tmat = (const float*)d_in[3];
    float* out = (float*)d_out;
    dim3 grid(4 * TILES);
    dim3 block(NTHR);
    hipLaunchKernelGGL(atten_fused, grid, block, 0, stream, x, tmat, out);
}